// Round 5
// baseline (111.047 us; speedup 1.0000x reference)
//
#include <hip/hip_runtime.h>
#include <hip/hip_bf16.h>

namespace {

constexpr int Hh    = 16;
constexpr int LL    = 4096;
constexpr int DD    = 64;
constexpr int BH    = 64;            // B*H
constexpr int CHUNK = 64;            // rows per block
constexpr int NCH   = LL / CHUNK;    // 64 chunks per (b,h)
constexpr int RPT   = 4;             // rows per 16-lane team
constexpr int RECF  = 128;           // floats per ws record (64 k-sums | 64 kv-sums)
constexpr float EPS = 1e-6f;

typedef __attribute__((ext_vector_type(4))) float f32x4;

__device__ __forceinline__ float elu1(float x) {
    return x > 0.0f ? x + 1.0f : __expf(x);
}

// --- 16-lane team butterfly sum (teams are 16-lane aligned within the wave) ---
template<int CTRL>
__device__ __forceinline__ float dpp_xor_add(float x) {
    int yi = __builtin_amdgcn_update_dpp(0, __float_as_int(x), CTRL, 0xF, 0xF, true);
    return x + __int_as_float(yi);
}
template<int IMM>
__device__ __forceinline__ float swz_xor_add(float x) {
    int yi = __builtin_amdgcn_ds_swizzle(__float_as_int(x), IMM);
    return x + __int_as_float(yi);
}
__device__ __forceinline__ float team_sum16(float x) {
    x = dpp_xor_add<0xB1>(x);      // quad_perm xor 1
    x = dpp_xor_add<0x4E>(x);      // quad_perm xor 2
    x = swz_xor_add<0x101F>(x);    // ds_swizzle xor 4
    x = swz_xor_add<0x201F>(x);    // ds_swizzle xor 8
    return x;
}

__device__ __forceinline__ float4 f4add(float4 a, float4 b) {
    return make_float4(a.x + b.x, a.y + b.y, a.z + b.z, a.w + b.w);
}

// ============================================================================
// Pass 1: per-chunk (64-row) totals of kf and kf*vm -> ws[bh*NCH+ch][128]
// ============================================================================
__global__ __launch_bounds__(256) void la_pass1(
    const float* __restrict__ kp, const float* __restrict__ vp,
    const float* __restrict__ maskp, float* __restrict__ ws)
{
    const int blk  = blockIdx.x;
    const int bh   = blk >> 6;          // / NCH
    const int ch   = blk & (NCH - 1);
    const int b    = bh >> 4;           // / Hh
    const int t    = threadIdx.x;
    const int qd   = t & 15;
    const int team = t >> 4;

    const long base  = ((long)bh * LL + (long)ch * CHUNK) * DD;
    const long rbase = base + (long)team * RPT * DD + qd * 4;
    const float* mrow = maskp + (long)b * LL + (long)ch * CHUNK + team * RPT;

    float4 sk = make_float4(0.f, 0.f, 0.f, 0.f);
    float4 sv = make_float4(0.f, 0.f, 0.f, 0.f);

    #pragma unroll
    for (int r = 0; r < RPT; ++r) {
        const float4 k4 = *(const float4*)(kp + rbase + (long)r * DD);
        const float4 v4 = *(const float4*)(vp + rbase + (long)r * DD);
        const float  m  = mrow[r];
        const float kf0 = elu1(k4.x) * m;
        const float kf1 = elu1(k4.y) * m;
        const float kf2 = elu1(k4.z) * m;
        const float kf3 = elu1(k4.w) * m;
        sk.x += kf0;              sk.y += kf1;
        sk.z += kf2;              sk.w += kf3;
        sv.x += kf0 * (v4.x * m); sv.y += kf1 * (v4.y * m);
        sv.z += kf2 * (v4.z * m); sv.w += kf3 * (v4.w * m);
    }

    __shared__ float red[16][RECF];
    red[team][qd*4+0] = sk.x; red[team][qd*4+1] = sk.y;
    red[team][qd*4+2] = sk.z; red[team][qd*4+3] = sk.w;
    red[team][64+qd*4+0] = sv.x; red[team][64+qd*4+1] = sv.y;
    red[team][64+qd*4+2] = sv.z; red[team][64+qd*4+3] = sv.w;
    __syncthreads();

    if (t < RECF) {
        float acc = 0.f;
        #pragma unroll
        for (int i = 0; i < 16; ++i) acc += red[i][t];
        ws[((long)bh * NCH + ch) * RECF + t] = acc;
    }
}

// ============================================================================
// Pass 2: small register tile (4 rows/team: kf,kv = 32 VGPR, q = 16 VGPR),
// carry from ws overlapped with tile loads, in-block team scan, serial 4-row
// scan + nontemporal output. __launch_bounds__(256,6): VGPR<=84, no spill.
// ============================================================================
__global__ __launch_bounds__(256, 6) void la_pass2(
    const float* __restrict__ qp, const float* __restrict__ kp,
    const float* __restrict__ vp, const float* __restrict__ maskp,
    const float* __restrict__ ws, float* __restrict__ outp)
{
    const int blk  = blockIdx.x;
    const int bh   = blk >> 6;          // / NCH
    const int ch   = blk & (NCH - 1);
    const int b    = bh >> 4;
    const int t    = threadIdx.x;
    const int qd   = t & 15;
    const int team = t >> 4;

    const long base  = ((long)bh * LL + (long)ch * CHUNK) * DD;
    const long rbase = base + (long)team * RPT * DD + qd * 4;
    const float* mrow = maskp + (long)b * LL + (long)ch * CHUNK + team * RPT;

    // ---- issue the tile loads (8 + 4 float4 + mask) before the carry loop ----
    float4 kb[RPT], vb[RPT], qb[RPT];
    float  mv[RPT];
    #pragma unroll
    for (int r = 0; r < RPT; ++r) {
        kb[r] = *(const float4*)(kp + rbase + (long)r * DD);
        vb[r] = *(const float4*)(vp + rbase + (long)r * DD);
        qb[r] = *(const float4*)(qp + rbase + (long)r * DD);
        mv[r] = mrow[r];
    }

    // ---- carry: sum of preceding chunk totals (L2-hot, overlaps tile loads) ----
    float4 ck = make_float4(0.f, 0.f, 0.f, 0.f);
    float4 cv = make_float4(0.f, 0.f, 0.f, 0.f);
    const float* wb = ws + (long)bh * NCH * RECF;
    for (int c = 0; c < ch; ++c) {
        const float* rec = wb + (long)c * RECF;
        ck = f4add(ck, *(const float4*)(rec + qd * 4));
        cv = f4add(cv, *(const float4*)(rec + 64 + qd * 4));
    }

    // ---- transform in place: kb <- kf = elu1(k)*m, vb <- kv = kf*(v*m) ----
    #pragma unroll
    for (int r = 0; r < RPT; ++r) {
        const float m = mv[r];
        float4 f;
        f.x = elu1(kb[r].x) * m; f.y = elu1(kb[r].y) * m;
        f.z = elu1(kb[r].z) * m; f.w = elu1(kb[r].w) * m;
        float4 g;
        g.x = f.x * (vb[r].x * m); g.y = f.y * (vb[r].y * m);
        g.z = f.z * (vb[r].z * m); g.w = f.w * (vb[r].w * m);
        kb[r] = f;
        vb[r] = g;
    }

    // ---- team totals ----
    float4 tk = make_float4(0.f, 0.f, 0.f, 0.f);
    float4 tv = make_float4(0.f, 0.f, 0.f, 0.f);
    #pragma unroll
    for (int r = 0; r < RPT; ++r) { tk = f4add(tk, kb[r]); tv = f4add(tv, vb[r]); }

    // ---- in-block exclusive scan over the 16 teams ----
    __shared__ float red[16][RECF];
    __shared__ float pre[16][RECF];
    red[team][qd*4+0] = tk.x; red[team][qd*4+1] = tk.y;
    red[team][qd*4+2] = tk.z; red[team][qd*4+3] = tk.w;
    red[team][64+qd*4+0] = tv.x; red[team][64+qd*4+1] = tv.y;
    red[team][64+qd*4+2] = tv.z; red[team][64+qd*4+3] = tv.w;
    __syncthreads();
    if (t < RECF) {
        float acc = 0.f;
        #pragma unroll
        for (int i = 0; i < 16; ++i) { pre[i][t] = acc; acc += red[i][t]; }
    }
    __syncthreads();

    float4 rk, rv;
    rk.x = ck.x + pre[team][qd*4+0]; rk.y = ck.y + pre[team][qd*4+1];
    rk.z = ck.z + pre[team][qd*4+2]; rk.w = ck.w + pre[team][qd*4+3];
    rv.x = cv.x + pre[team][64+qd*4+0]; rv.y = cv.y + pre[team][64+qd*4+1];
    rv.z = cv.z + pre[team][64+qd*4+2]; rv.w = cv.w + pre[team][64+qd*4+3];

    // ---- serial scan over the team's 4 rows, emit output ----
    #pragma unroll
    for (int r = 0; r < RPT; ++r) {
        rk = f4add(rk, kb[r]);
        rv = f4add(rv, vb[r]);

        float4 qf;
        qf.x = elu1(qb[r].x); qf.y = elu1(qb[r].y);
        qf.z = elu1(qb[r].z); qf.w = elu1(qb[r].w);

        float pz = qf.x*rk.x + qf.y*rk.y + qf.z*rk.z + qf.w*rk.w;
        pz = team_sum16(pz);

        const float z   = (pz + EPS) * mv[r];
        const float inv = __builtin_amdgcn_rcpf(z);

        f32x4 o;
        o.x = qf.x * rv.x * inv;
        o.y = qf.y * rv.y * inv;
        o.z = qf.z * rv.z * inv;
        o.w = qf.w * rv.w * inv;
        __builtin_nontemporal_store(o, (f32x4*)(outp + rbase + (long)r * DD));
    }
}

} // namespace

extern "C" void kernel_launch(void* const* d_in, const int* in_sizes, int n_in,
                              void* d_out, int out_size, void* d_ws, size_t ws_size,
                              hipStream_t stream) {
    const float* q    = (const float*)d_in[0];
    const float* k    = (const float*)d_in[1];
    const float* v    = (const float*)d_in[2];
    const float* mask = (const float*)d_in[3];
    float* out = (float*)d_out;
    float* ws  = (float*)d_ws;   // needs BH*NCH*RECF floats = 2 MiB

    dim3 grid(BH * NCH);
    dim3 block(256);
    la_pass1<<<grid, block, 0, stream>>>(k, v, mask, ws);
    la_pass2<<<grid, block, 0, stream>>>(q, k, v, mask, ws, out);
}

// Round 6
// 67.093 us; speedup vs baseline: 1.6551x; 1.6551x over previous
//
#include <hip/hip_runtime.h>
#include <hip/hip_bf16.h>

namespace {

constexpr int Hh    = 16;
constexpr int LL    = 4096;
constexpr int DD    = 64;
constexpr int BH    = 64;            // B*H
constexpr int CHUNK = 128;           // rows per block
constexpr int NCH   = LL / CHUNK;    // 32 chunks per (b,h)
constexpr int RPT   = 8;             // rows per 16-lane team
constexpr int RECF  = 128;           // floats per ws record (64 k-sums | 64 kv-sums)
constexpr float EPS = 1e-6f;

typedef __attribute__((ext_vector_type(4))) float f32x4;

__device__ __forceinline__ float elu1(float x) {
    return x > 0.0f ? x + 1.0f : __expf(x);
}

// --- 16-lane team butterfly sum (teams are 16-lane aligned within the wave) ---
template<int CTRL>
__device__ __forceinline__ float dpp_xor_add(float x) {
    int yi = __builtin_amdgcn_update_dpp(0, __float_as_int(x), CTRL, 0xF, 0xF, true);
    return x + __int_as_float(yi);
}
template<int IMM>
__device__ __forceinline__ float swz_xor_add(float x) {
    int yi = __builtin_amdgcn_ds_swizzle(__float_as_int(x), IMM);
    return x + __int_as_float(yi);
}
__device__ __forceinline__ float team_sum16(float x) {
    x = dpp_xor_add<0xB1>(x);      // quad_perm xor 1
    x = dpp_xor_add<0x4E>(x);      // quad_perm xor 2
    x = swz_xor_add<0x101F>(x);    // ds_swizzle xor 4
    x = swz_xor_add<0x201F>(x);    // ds_swizzle xor 8
    return x;
}

__device__ __forceinline__ float4 f4add(float4 a, float4 b) {
    return make_float4(a.x + b.x, a.y + b.y, a.z + b.z, a.w + b.w);
}

// ============================================================================
// Pass 1: per-chunk (128-row) totals of kf and kf*vm -> ws[bh*NCH+ch][128]
// ============================================================================
__global__ __launch_bounds__(256) void la_pass1(
    const float* __restrict__ kp, const float* __restrict__ vp,
    const float* __restrict__ maskp, float* __restrict__ ws)
{
    const int blk  = blockIdx.x;
    const int bh   = blk >> 5;          // / NCH
    const int ch   = blk & (NCH - 1);
    const int b    = bh >> 4;           // / Hh
    const int t    = threadIdx.x;
    const int qd   = t & 15;
    const int team = t >> 4;

    const long base  = ((long)bh * LL + (long)ch * CHUNK) * DD;
    const long rbase = base + (long)team * RPT * DD + qd * 4;
    const float* mrow = maskp + (long)b * LL + (long)ch * CHUNK + team * RPT;

    float4 sk = make_float4(0.f, 0.f, 0.f, 0.f);
    float4 sv = make_float4(0.f, 0.f, 0.f, 0.f);

    #pragma unroll
    for (int r = 0; r < RPT; ++r) {
        const float4 k4 = *(const float4*)(kp + rbase + (long)r * DD);
        const float4 v4 = *(const float4*)(vp + rbase + (long)r * DD);
        const float  m  = mrow[r];
        const float kf0 = elu1(k4.x) * m;
        const float kf1 = elu1(k4.y) * m;
        const float kf2 = elu1(k4.z) * m;
        const float kf3 = elu1(k4.w) * m;
        sk.x += kf0;              sk.y += kf1;
        sk.z += kf2;              sk.w += kf3;
        sv.x += kf0 * (v4.x * m); sv.y += kf1 * (v4.y * m);
        sv.z += kf2 * (v4.z * m); sv.w += kf3 * (v4.w * m);
    }

    __shared__ float red[16][RECF];
    red[team][qd*4+0] = sk.x; red[team][qd*4+1] = sk.y;
    red[team][qd*4+2] = sk.z; red[team][qd*4+3] = sk.w;
    red[team][64+qd*4+0] = sv.x; red[team][64+qd*4+1] = sv.y;
    red[team][64+qd*4+2] = sv.z; red[team][64+qd*4+3] = sv.w;
    __syncthreads();

    if (t < RECF) {
        float acc = 0.f;
        #pragma unroll
        for (int i = 0; i < 16; ++i) acc += red[i][t];
        ws[((long)bh * NCH + ch) * RECF + t] = acc;
    }
}

// ============================================================================
// Pass 1.5: in-place exclusive scan of the NCH chunk-total records per (b,h).
// One block per bh; thread t owns float-column t of every record.
// ============================================================================
__global__ __launch_bounds__(RECF) void la_scan(float* __restrict__ ws)
{
    const int bh = blockIdx.x;
    const int t  = threadIdx.x;
    float* wb = ws + (long)bh * NCH * RECF + t;

    float vals[NCH];
    #pragma unroll
    for (int c = 0; c < NCH; ++c) vals[c] = wb[(long)c * RECF];  // batched loads

    float acc = 0.f;
    #pragma unroll
    for (int c = 0; c < NCH; ++c) {
        const float x = vals[c];
        wb[(long)c * RECF] = acc;      // exclusive prefix
        acc += x;
    }
}

// ============================================================================
// Pass 2: no carry loop. Read ONE prefix record, batched k/v tile loads
// (pass1-shaped), in-block team scan, q loads drained under the scan,
// serial 8-row scan + nontemporal output.
// ============================================================================
__global__ __launch_bounds__(256, 4) void la_pass2(
    const float* __restrict__ qp, const float* __restrict__ kp,
    const float* __restrict__ vp, const float* __restrict__ maskp,
    const float* __restrict__ ws, float* __restrict__ outp)
{
    const int blk  = blockIdx.x;
    const int bh   = blk >> 5;          // / NCH
    const int ch   = blk & (NCH - 1);
    const int b    = bh >> 4;
    const int t    = threadIdx.x;
    const int qd   = t & 15;
    const int team = t >> 4;

    const long base  = ((long)bh * LL + (long)ch * CHUNK) * DD;
    const long rbase = base + (long)team * RPT * DD + qd * 4;
    const float* mrow = maskp + (long)b * LL + (long)ch * CHUNK + team * RPT;

    // ---- own exclusive-prefix record (512 B, L2-hot), issued first ----
    const float* rec = ws + ((long)bh * NCH + ch) * RECF;
    const float4 ck = *(const float4*)(rec + qd * 4);
    const float4 cv = *(const float4*)(rec + 64 + qd * 4);

    // ---- k/v tile burst: 16 float4, identical shape to pass1's load phase ----
    float4 kb[RPT], vb[RPT];
    float  mv[RPT];
    #pragma unroll
    for (int r = 0; r < RPT; ++r) {
        kb[r] = *(const float4*)(kp + rbase + (long)r * DD);
        vb[r] = *(const float4*)(vp + rbase + (long)r * DD);
        mv[r] = mrow[r];
    }

    // ---- transform in place: kb <- kf = elu1(k)*m, vb <- kv = kf*(v*m) ----
    #pragma unroll
    for (int r = 0; r < RPT; ++r) {
        const float m = mv[r];
        float4 f;
        f.x = elu1(kb[r].x) * m; f.y = elu1(kb[r].y) * m;
        f.z = elu1(kb[r].z) * m; f.w = elu1(kb[r].w) * m;
        float4 g;
        g.x = f.x * (vb[r].x * m); g.y = f.y * (vb[r].y * m);
        g.z = f.z * (vb[r].z * m); g.w = f.w * (vb[r].w * m);
        kb[r] = f;
        vb[r] = g;
    }

    // ---- team totals ----
    float4 tk = make_float4(0.f, 0.f, 0.f, 0.f);
    float4 tv = make_float4(0.f, 0.f, 0.f, 0.f);
    #pragma unroll
    for (int r = 0; r < RPT; ++r) { tk = f4add(tk, kb[r]); tv = f4add(tv, vb[r]); }

    __shared__ float red[16][RECF];
    __shared__ float pre[16][RECF];
    red[team][qd*4+0] = tk.x; red[team][qd*4+1] = tk.y;
    red[team][qd*4+2] = tk.z; red[team][qd*4+3] = tk.w;
    red[team][64+qd*4+0] = tv.x; red[team][64+qd*4+1] = tv.y;
    red[team][64+qd*4+2] = tv.z; red[team][64+qd*4+3] = tv.w;

    // ---- q burst: 8 float4, issued before the barrier; drains under the scan ----
    float4 qb[RPT];
    #pragma unroll
    for (int r = 0; r < RPT; ++r)
        qb[r] = *(const float4*)(qp + rbase + (long)r * DD);

    __syncthreads();
    if (t < RECF) {
        float acc = 0.f;
        #pragma unroll
        for (int i = 0; i < 16; ++i) { pre[i][t] = acc; acc += red[i][t]; }
    }
    __syncthreads();

    float4 rk, rv;
    rk.x = ck.x + pre[team][qd*4+0]; rk.y = ck.y + pre[team][qd*4+1];
    rk.z = ck.z + pre[team][qd*4+2]; rk.w = ck.w + pre[team][qd*4+3];
    rv.x = cv.x + pre[team][64+qd*4+0]; rv.y = cv.y + pre[team][64+qd*4+1];
    rv.z = cv.z + pre[team][64+qd*4+2]; rv.w = cv.w + pre[team][64+qd*4+3];

    // ---- serial scan over the team's 8 rows, emit output ----
    #pragma unroll
    for (int r = 0; r < RPT; ++r) {
        rk = f4add(rk, kb[r]);
        rv = f4add(rv, vb[r]);

        float4 qf;
        qf.x = elu1(qb[r].x); qf.y = elu1(qb[r].y);
        qf.z = elu1(qb[r].z); qf.w = elu1(qb[r].w);

        float pz = qf.x*rk.x + qf.y*rk.y + qf.z*rk.z + qf.w*rk.w;
        pz = team_sum16(pz);

        const float z   = (pz + EPS) * mv[r];
        const float inv = __builtin_amdgcn_rcpf(z);

        f32x4 o;
        o.x = qf.x * rv.x * inv;
        o.y = qf.y * rv.y * inv;
        o.z = qf.z * rv.z * inv;
        o.w = qf.w * rv.w * inv;
        __builtin_nontemporal_store(o, (f32x4*)(outp + rbase + (long)r * DD));
    }
}

} // namespace

extern "C" void kernel_launch(void* const* d_in, const int* in_sizes, int n_in,
                              void* d_out, int out_size, void* d_ws, size_t ws_size,
                              hipStream_t stream) {
    const float* q    = (const float*)d_in[0];
    const float* k    = (const float*)d_in[1];
    const float* v    = (const float*)d_in[2];
    const float* mask = (const float*)d_in[3];
    float* out = (float*)d_out;
    float* ws  = (float*)d_ws;   // needs BH*NCH*RECF floats = 1 MiB

    la_pass1<<<dim3(BH * NCH), dim3(256), 0, stream>>>(k, v, mask, ws);
    la_scan <<<dim3(BH),       dim3(RECF), 0, stream>>>(ws);
    la_pass2<<<dim3(BH * NCH), dim3(256), 0, stream>>>(q, k, v, mask, ws, out);
}